// Round 3
// 1714.119 us; speedup vs baseline: 1.0171x; 1.0171x over previous
//
#include <hip/hip_runtime.h>
#include <stdint.h>

#define NOBJ 20000
#define NTRI 100000

typedef unsigned short ushort_t;
typedef __attribute__((ext_vector_type(8))) short short8;
typedef __attribute__((ext_vector_type(4))) float float4v;

enum { MODE_H = 0, MODE_G = 2, MODE_OBJ = 3, MODE_PRED = 4, MODE_SO = 5, MODE_P = 6 };

__device__ __forceinline__ ushort_t f2bf(float f) {
    union { float f; unsigned int i; } x;
    x.f = f;
    unsigned int r = x.i + 0x7fffu + ((x.i >> 16) & 1u);  // RNE
    return (ushort_t)(r >> 16);
}

__device__ __forceinline__ void gload_lds16(const ushort_t* g, short8* l) {
    __builtin_amdgcn_global_load_lds((const __attribute__((address_space(1))) void*)g,
                                     (__attribute__((address_space(3))) void*)l,
                                     16, 0, 0);
}

// fp32 -> bf16 conversion, 4 elements/thread
__global__ void __launch_bounds__(256) cvt_k(const float* __restrict__ src,
                                             ushort_t* __restrict__ dst, int n4) {
    int i = blockIdx.x * 256 + threadIdx.x;
    if (i >= n4) return;
    const float4* s4 = (const float4*)src;
    float4 v = s4[i];
    ushort_t o[4] = {f2bf(v.x), f2bf(v.y), f2bf(v.z), f2bf(v.w)};
    *(uint64_t*)(dst + 4 * (size_t)i) = *(const uint64_t*)o;
}

// ---- CSR (counting sort of edge endpoints by object) ----
__global__ void __launch_bounds__(256) hist_k(const int* __restrict__ edges,
                                              int* __restrict__ counts_s,
                                              int* __restrict__ counts_o, int n2) {
    int i = blockIdx.x * 256 + threadIdx.x;
    if (i >= n2) return;
    int obj = edges[i];
    if (i & 1) atomicAdd(&counts_o[obj], 1);
    else       atomicAdd(&counts_s[obj], 1);
}

// single-block exclusive scan of n=20000 ints -> offs[n+1], cur = offs copy
__global__ void __launch_bounds__(256) scan_k(const int* __restrict__ counts,
                                              int* __restrict__ offs,
                                              int* __restrict__ cur, int n) {
    __shared__ int lds[256];
    const int CHUNK = 80;  // 256*80 = 20480 >= 20001
    int t = threadIdx.x;
    int base = t * CHUNK;
    int s = 0;
    for (int j = 0; j < CHUNK; ++j) {
        int i = base + j;
        if (i < n) s += counts[i];
    }
    lds[t] = s;
    __syncthreads();
    for (int off = 1; off < 256; off <<= 1) {
        int v = (t >= off) ? lds[t - off] : 0;
        __syncthreads();
        lds[t] += v;
        __syncthreads();
    }
    int run = lds[t] - s;  // exclusive prefix
    for (int j = 0; j < CHUNK; ++j) {
        int i = base + j;
        if (i < n) {
            offs[i] = run;
            cur[i] = run;
            run += counts[i];
        } else if (i == n) {
            offs[n] = run;
        }
    }
}

__global__ void __launch_bounds__(256) fill_k(const int* __restrict__ edges,
                                              int* __restrict__ cur_s, int* __restrict__ cur_o,
                                              int* __restrict__ perm_s, int* __restrict__ perm_o,
                                              int n) {
    int t = blockIdx.x * 256 + threadIdx.x;
    if (t >= n) return;
    int s = edges[2 * t];
    int o = edges[2 * t + 1];
    perm_s[atomicAdd(&cur_s[s], 1)] = t;
    perm_o[atomicAdd(&cur_o[o], 1)] = t;
}

// ---- streaming pool: one wave per object, contiguous CSR range, no atomics ----
// nst is in SORTED order (the SO-GEMM gathered A-rows through perm), so object
// `obj` owns the contiguous row range [offs[obj], offs[obj+1]).
// PASS 0: pooled[obj] = sum of nst rows (s endpoints), fp32
// PASS 1: pooled = (pooled + sum of o rows) / max(deg,1), fp32, in place at
//         identical per-lane addresses (no layout/width tricks).
template <int PASS>
__global__ void __launch_bounds__(256)
pool_k(const ushort_t* __restrict__ nst, const int* __restrict__ offs_s,
       const int* __restrict__ offs_o, float* __restrict__ pooled) {
    int wave = threadIdx.x >> 6;
    int lane = threadIdx.x & 63;
    int obj = blockIdx.x * 4 + wave;
    if (obj >= NOBJ) return;
    const int* offs = (PASS == 0) ? offs_s : offs_o;
    int s = offs[obj], e = offs[obj + 1];
    float acc[8];
#pragma unroll
    for (int j = 0; j < 8; ++j) acc[j] = 0.f;
    for (int i = s; i < e; ++i) {
        uint4 v = *(const uint4*)(nst + (size_t)i * 512 + lane * 8);  // 8 bf16 / lane
        acc[0] += __uint_as_float(v.x << 16);
        acc[1] += __uint_as_float(v.x & 0xffff0000u);
        acc[2] += __uint_as_float(v.y << 16);
        acc[3] += __uint_as_float(v.y & 0xffff0000u);
        acc[4] += __uint_as_float(v.z << 16);
        acc[5] += __uint_as_float(v.z & 0xffff0000u);
        acc[6] += __uint_as_float(v.w << 16);
        acc[7] += __uint_as_float(v.w & 0xffff0000u);
    }
    float* prow = pooled + (size_t)obj * 512 + lane * 8;
    if (PASS == 0) {
        *(float4*)(prow)     = make_float4(acc[0], acc[1], acc[2], acc[3]);
        *(float4*)(prow + 4) = make_float4(acc[4], acc[5], acc[6], acc[7]);
    } else {
        float4 a0 = *(const float4*)(prow);
        float4 a1 = *(const float4*)(prow + 4);
        int deg = (offs_s[obj + 1] - offs_s[obj]) + (offs_o[obj + 1] - offs_o[obj]);
        float inv = 1.f / (float)((deg > 1) ? deg : 1);
        *(float4*)(prow)     = make_float4((acc[0] + a0.x) * inv, (acc[1] + a0.y) * inv,
                                           (acc[2] + a0.z) * inv, (acc[3] + a0.w) * inv);
        *(float4*)(prow + 4) = make_float4((acc[4] + a1.x) * inv, (acc[5] + a1.y) * inv,
                                           (acc[6] + a1.z) * inv, (acc[7] + a1.w) * inv);
    }
}

// Generic 128x128 tile MFMA GEMM computing C[m][n] = sum_k A[m][k]*B[n][k]
// (A: M x K row-major bf16 with leading dim lda, B: N x K row-major bf16),
// mode-specialized A-source (fused gathers) and epilogue.
template <int MODE>
__global__ void __launch_bounds__(256)
gtc_gemm(const ushort_t* __restrict__ A, const ushort_t* __restrict__ Bw,
         const float* __restrict__ bias,
         const ushort_t* __restrict__ A2, const ushort_t* __restrict__ B2,
         const float* __restrict__ bias2,
         const int* __restrict__ idx,   // edges (MODE_H) or row-permutation (MODE_SO)
         const ushort_t* __restrict__ objv, const ushort_t* __restrict__ predv,
         const float* __restrict__ addend,
         void* __restrict__ outv,
         int M, int K, int lda)
{
    // LDS granule layout [kg][row], 16B granules, kg-major: fragment
    // ds_read_b128 is conflict-free.
    __shared__ short8 sA[1024];   // 16 KB
    __shared__ short8 sB[1024];   // 16 KB
    __shared__ int sIdx[128];
    __shared__ int oIdx[128];

    const int tid  = threadIdx.x;
    const int lane = tid & 63;
    const int wave = tid >> 6;
    const int wm   = wave & 1;
    const int wn   = wave >> 1;
    const int quad = lane >> 4;
    const int lr   = lane & 15;
    const int m0   = blockIdx.y * 128;
    const int n0   = blockIdx.x * 128;

    if (MODE == MODE_H) {
        if (tid < 128) {
            int t = m0 + tid;
            if (t >= M) t = M - 1;
            sIdx[tid] = idx[2 * t];
            oIdx[tid] = idx[2 * t + 1];
        }
        __syncthreads();
    } else if (MODE == MODE_SO) {
        if (tid < 128) {
            int t = m0 + tid;
            if (t >= M) t = M - 1;
            sIdx[tid] = idx[t];
        }
        __syncthreads();
    }

    float4v acc[4][4];
#pragma unroll
    for (int i = 0; i < 4; ++i)
#pragma unroll
        for (int j = 0; j < 4; ++j)
            acc[i][j] = (float4v){0.f, 0.f, 0.f, 0.f};

    const int npass = (MODE == MODE_OBJ) ? 2 : 1;
    for (int pass = 0; pass < npass; ++pass) {
        const ushort_t* Ap = (pass == 0) ? A : A2;
        const ushort_t* Bp = (pass == 0) ? Bw : B2;

        for (int k0 = 0; k0 < K; k0 += 64) {
            __syncthreads();  // previous tile's compute done before restage
            // ---- stage A tile (128 rows x 64 k) ----
#pragma unroll
            for (int i = 0; i < 4; ++i) {
                int g  = i * 256 + tid;       // granule = kg*128 + m
                int kg = g >> 7;              // wave-uniform
                int m  = g & 127;
                int krow = k0 + kg * 8;
                const ushort_t* src;
                if (MODE == MODE_H) {
                    int t = m0 + m;
                    if (t >= M) t = M - 1;
                    if (krow < 512)
                        src = objv + (size_t)sIdx[m] * 512 + krow;
                    else if (krow < 1024)
                        src = predv + (size_t)t * 512 + (krow - 512);
                    else
                        src = objv + (size_t)oIdx[m] * 512 + (krow - 1024);
                } else if (MODE == MODE_SO) {
                    src = Ap + (size_t)sIdx[m] * (size_t)K + krow;  // gathered h rows
                } else {
                    int r = m0 + m;
                    if (r >= M) r = M - 1;
                    src = Ap + (size_t)r * (size_t)lda + krow;
                }
                gload_lds16(src, &sA[g]);
            }
            // ---- stage B tile (128 n x 64 k) ----
#pragma unroll
            for (int i = 0; i < 4; ++i) {
                int g  = i * 256 + tid;
                int kg = g >> 7;
                int n  = g & 127;
                gload_lds16(Bp + (size_t)(n0 + n) * K + k0 + kg * 8, &sB[g]);
            }
            __syncthreads();  // staging drained

#pragma unroll
            for (int kk = 0; kk < 2; ++kk) {
                short8 af[4], bfv[4];
#pragma unroll
                for (int t = 0; t < 4; ++t)
                    af[t] = sA[(kk * 4 + quad) * 128 + wm * 64 + t * 16 + lr];
#pragma unroll
                for (int t = 0; t < 4; ++t)
                    bfv[t] = sB[(kk * 4 + quad) * 128 + wn * 64 + t * 16 + lr];
#pragma unroll
                for (int ti = 0; ti < 4; ++ti)
#pragma unroll
                    for (int tj = 0; tj < 4; ++tj)
                        acc[ti][tj] = __builtin_amdgcn_mfma_f32_16x16x32_bf16(
                            af[ti], bfv[tj], acc[ti][tj], 0, 0, 0);
            }
        }

        if (MODE == MODE_OBJ && pass == 0) {
            // acc = relu(acc + c2[col]) between the two fused GEMMs
#pragma unroll
            for (int tj = 0; tj < 4; ++tj) {
                float b = bias[n0 + wn * 64 + tj * 16 + lr];
#pragma unroll
                for (int ti = 0; ti < 4; ++ti)
#pragma unroll
                    for (int r = 0; r < 4; ++r)
                        acc[ti][tj][r] = fmaxf(acc[ti][tj][r] + b, 0.f);
            }
        }
    }

    // ---- epilogue ----
    float bcol[4];
#pragma unroll
    for (int tj = 0; tj < 4; ++tj) {
        int col = n0 + wn * 64 + tj * 16 + lr;
        const float* bptr = (MODE == MODE_OBJ) ? bias2 : bias;
        bcol[tj] = bptr[col];
    }

#pragma unroll
    for (int ti = 0; ti < 4; ++ti) {
#pragma unroll
        for (int r = 0; r < 4; ++r) {
            int row = m0 + wm * 64 + ti * 16 + quad * 4 + r;
            if (row >= M) continue;
#pragma unroll
            for (int tj = 0; tj < 4; ++tj) {
                int col = n0 + wn * 64 + tj * 16 + lr;
                float v = acc[ti][tj][r];
                if (MODE == MODE_H || MODE == MODE_G || MODE == MODE_SO) {
                    v = fmaxf(v + bcol[tj], 0.f);
                    ((ushort_t*)outv)[(size_t)row * 512 + col] = f2bf(v);
                } else if (MODE == MODE_P) {
                    // relu(h@W2_p + b2_p) + (pred@Ppred + pbpred), in place
                    v = fmaxf(v + bcol[tj], 0.f) + addend[(size_t)row * 512 + col];
                    ((float*)outv)[(size_t)row * 512 + col] = v;
                } else if (MODE == MODE_OBJ) {
                    ((float*)outv)[(size_t)row * 512 + col] = v + bcol[tj];
                } else {  // MODE_PRED
                    v = v + bcol[tj];
                    if (addend) v += addend[(size_t)row * 512 + col];
                    ((float*)outv)[(size_t)row * 512 + col] = v;
                }
            }
        }
    }
}

extern "C" void kernel_launch(void* const* d_in, const int* in_sizes, int n_in,
                              void* d_out, int out_size, void* d_ws, size_t ws_size,
                              hipStream_t stream) {
    const float* obj    = (const float*)d_in[0];
    const float* pred   = (const float*)d_in[1];
    const int*   edges  = (const int*)d_in[2];
    const float* W1     = (const float*)d_in[3];
    const float* b1     = (const float*)d_in[4];
    const float* W2     = (const float*)d_in[5];
    const float* b2     = (const float*)d_in[6];
    const float* V1     = (const float*)d_in[7];
    const float* c1     = (const float*)d_in[8];
    const float* V2     = (const float*)d_in[9];
    const float* c2     = (const float*)d_in[10];
    const float* Pobj   = (const float*)d_in[11];
    const float* pbobj  = (const float*)d_in[12];
    const float* Ppred  = (const float*)d_in[13];
    const float* pbpred = (const float*)d_in[14];

    // ---- workspace layout (total 230,522,880 B — within the known-good
    // 230.6 MB footprint) ----
    char* ws = (char*)d_ws;
    ushort_t* h       = (ushort_t*)(ws + 0);              // 102,400,000 B (dead after MODE_P)
    ushort_t* bfPred  = (ushort_t*)(ws + 102400000);      // 102,400,000 B (dead after GEMM1+P0)
    ushort_t* nst     = bfPred;                           // new_s / new_o bf16, aliases bfPred
    ushort_t* bfObj   = (ushort_t*)(ws + 204800000);      //  20,480,000 B
    ushort_t* bfW1    = (ushort_t*)(ws + 225280000);      //   1,572,864 B (dead after GEMM1)
    // CSR structures alias the dead bfW1 region (built after GEMM1):
    char* csr = ws + 225280000;
    int* counts_s = (int*)(csr + 0);        //  80,000 B
    int* counts_o = (int*)(csr + 80000);    //  80,000 B
    int* offs_s   = (int*)(csr + 160000);   //  80,064 B (20001 ints)
    int* offs_o   = (int*)(csr + 240064);   //  80,064 B
    int* cur_s    = (int*)(csr + 320128);   //  80,000 B
    int* cur_o    = (int*)(csr + 400128);   //  80,000 B
    int* perm_s   = (int*)(csr + 480128);   // 400,000 B
    int* perm_o   = (int*)(csr + 880128);   // 400,000 B -> ends +1,280,128 < 1,572,864
    ushort_t* bfW2    = (ushort_t*)(ws + 226852864);      //   1,572,864 B
    ushort_t* bfV1    = (ushort_t*)(ws + 228425728);      //     524,288 B
    ushort_t* bfV2    = (ushort_t*)(ws + 228950016);      //     524,288 B
    ushort_t* bfPobj  = (ushort_t*)(ws + 229474304);      //     524,288 B
    ushort_t* bfPpred = (ushort_t*)(ws + 229998592);      //     524,288 B -> 230,522,880
    // aliases into the dead h region (only touched after MODE_P retires h):
    ushort_t* pooledn = (ushort_t*)(ws + 0);              //  20,480,000 B
    ushort_t* gbuf    = (ushort_t*)(ws + 20480000);       //  20,480,000 B

    float* out_obj = (float*)d_out;
    float* out_p   = out_obj + (size_t)NOBJ * 512;
    // fp32 pooled accumulators live in the out_obj region of d_out (exactly
    // 40,960,000 B); dead after the cvt to pooledn; MODE_OBJ then overwrites.
    float* pooled = out_obj;

    // fp32 -> bf16 conversions
    cvt_k<<<dim3(10000), dim3(256), 0, stream>>>(obj,   bfObj,   10240000 / 4);
    cvt_k<<<dim3(50000), dim3(256), 0, stream>>>(pred,  bfPred,  51200000 / 4);
    cvt_k<<<dim3(768),   dim3(256), 0, stream>>>(W1,    bfW1,    786432 / 4);
    cvt_k<<<dim3(768),   dim3(256), 0, stream>>>(W2,    bfW2,    786432 / 4);
    cvt_k<<<dim3(256),   dim3(256), 0, stream>>>(V1,    bfV1,    262144 / 4);
    cvt_k<<<dim3(256),   dim3(256), 0, stream>>>(V2,    bfV2,    262144 / 4);
    cvt_k<<<dim3(256),   dim3(256), 0, stream>>>(Pobj,  bfPobj,  262144 / 4);
    cvt_k<<<dim3(256),   dim3(256), 0, stream>>>(Ppred, bfPpred, 262144 / 4);

    // P0: out_p = pred @ Ppred^T + pbpred (frees bfPred for the nst alias)
    gtc_gemm<MODE_PRED><<<dim3(4, 782), dim3(256), 0, stream>>>(
        bfPred, bfPpred, pbpred, nullptr, nullptr, nullptr,
        nullptr, nullptr, nullptr, nullptr, out_p, NTRI, 512, 512);

    // GEMM1: h = relu(gather(cur_t) @ W1^T + b1)    (100000 x 512, K=1536)
    gtc_gemm<MODE_H><<<dim3(4, 782), dim3(256), 0, stream>>>(
        nullptr, bfW1, b1, nullptr, nullptr, nullptr,
        edges, bfObj, bfPred, nullptr, h, NTRI, 1536, 1536);

    // ---- CSR build (bfW1 dead now) ----
    hipMemsetAsync(counts_s, 0, 160000, stream);  // counts_s + counts_o
    hist_k<<<dim3(782), dim3(256), 0, stream>>>(edges, counts_s, counts_o, 2 * NTRI);
    scan_k<<<dim3(1), dim3(256), 0, stream>>>(counts_s, offs_s, cur_s, NOBJ);
    scan_k<<<dim3(1), dim3(256), 0, stream>>>(counts_o, offs_o, cur_o, NOBJ);
    fill_k<<<dim3(391), dim3(256), 0, stream>>>(edges, cur_s, cur_o, perm_s, perm_o, NTRI);

    // GEMM2-s: new_s rows (permuted so same-object rows are contiguous) -> nst
    gtc_gemm<MODE_SO><<<dim3(4, 782), dim3(256), 0, stream>>>(
        h, bfW2, b2, nullptr, nullptr, nullptr,
        perm_s, nullptr, nullptr, nullptr, nst, NTRI, 512, 512);
    pool_k<0><<<dim3(5000), dim3(256), 0, stream>>>(nst, offs_s, offs_o, pooled);

    // GEMM2-o: new_o rows -> nst (reused)
    gtc_gemm<MODE_SO><<<dim3(4, 782), dim3(256), 0, stream>>>(
        h, bfW2 + 1024 * 512, b2 + 1024, nullptr, nullptr, nullptr,
        perm_o, nullptr, nullptr, nullptr, nst, NTRI, 512, 512);
    pool_k<1><<<dim3(5000), dim3(256), 0, stream>>>(nst, offs_s, offs_o, pooled);

    // GEMM2-p: out_p = relu(h @ W2_p^T + b2_p) + out_p  (fuses old GEMM6)
    // Last use of h.
    gtc_gemm<MODE_P><<<dim3(4, 782), dim3(256), 0, stream>>>(
        h, bfW2 + 512 * 512, b2 + 512, nullptr, nullptr, nullptr,
        nullptr, nullptr, nullptr, out_p, out_p, NTRI, 512, 512);

    // pooled fp32 -> pooledn bf16 (contiguous 512-stride, in dead h region)
    cvt_k<<<dim3(10000), dim3(256), 0, stream>>>(pooled, pooledn, 10240000 / 4);

    // GEMM3: g = relu(pooledn @ V1^T + c1)   (20000 x 512, K=512)
    gtc_gemm<MODE_G><<<dim3(4, 157), dim3(256), 0, stream>>>(
        pooledn, bfV1, c1, nullptr, nullptr, nullptr,
        nullptr, nullptr, nullptr, nullptr, gbuf, NOBJ, 512, 512);

    // GEMM4+5 fused: out_obj = relu(g @ V2^T + c2) + obj @ P_obj^T + pb_obj
    // (overwrites the pooled region — pooled is dead after the cvt)
    gtc_gemm<MODE_OBJ><<<dim3(4, 157), dim3(256), 0, stream>>>(
        gbuf, bfV2, c2, bfObj, bfPobj, pbobj,
        nullptr, nullptr, nullptr, nullptr, out_obj, NOBJ, 512, 512);
}

// Round 4
// 1591.068 us; speedup vs baseline: 1.0957x; 1.0773x over previous
//
#include <hip/hip_runtime.h>
#include <stdint.h>

#define NOBJ 20000
#define NTRI 100000

typedef unsigned short ushort_t;
typedef __attribute__((ext_vector_type(8))) short short8;
typedef __attribute__((ext_vector_type(4))) float float4v;

enum { MODE_H = 0, MODE_G = 2, MODE_OBJ = 3, MODE_SO = 5 };

__device__ __forceinline__ ushort_t f2bf(float f) {
    union { float f; unsigned int i; } x;
    x.f = f;
    unsigned int r = x.i + 0x7fffu + ((x.i >> 16) & 1u);  // RNE
    return (ushort_t)(r >> 16);
}

__device__ __forceinline__ void gload_lds16(const ushort_t* g, short8* l) {
    __builtin_amdgcn_global_load_lds((const __attribute__((address_space(1))) void*)g,
                                     (__attribute__((address_space(3))) void*)l,
                                     16, 0, 0);
}

// fp32 -> bf16 conversion, 4 elements/thread
__global__ void __launch_bounds__(256) cvt_k(const float* __restrict__ src,
                                             ushort_t* __restrict__ dst, int n4) {
    int i = blockIdx.x * 256 + threadIdx.x;
    if (i >= n4) return;
    const float4* s4 = (const float4*)src;
    float4 v = s4[i];
    ushort_t o[4] = {f2bf(v.x), f2bf(v.y), f2bf(v.z), f2bf(v.w)};
    *(uint64_t*)(dst + 4 * (size_t)i) = *(const uint64_t*)o;
}

// ---- CSR (counting sort of edge endpoints by object) ----
__global__ void __launch_bounds__(256) hist_k(const int* __restrict__ edges,
                                              int* __restrict__ counts_s,
                                              int* __restrict__ counts_o, int n2) {
    int i = blockIdx.x * 256 + threadIdx.x;
    if (i >= n2) return;
    int obj = edges[i];
    if (i & 1) atomicAdd(&counts_o[obj], 1);
    else       atomicAdd(&counts_s[obj], 1);
}

// single-block exclusive scan of n=20000 ints -> offs[n+1], cur = offs copy
__global__ void __launch_bounds__(256) scan_k(const int* __restrict__ counts,
                                              int* __restrict__ offs,
                                              int* __restrict__ cur, int n) {
    __shared__ int lds[256];
    const int CHUNK = 80;  // 256*80 = 20480 >= 20001
    int t = threadIdx.x;
    int base = t * CHUNK;
    int s = 0;
    for (int j = 0; j < CHUNK; ++j) {
        int i = base + j;
        if (i < n) s += counts[i];
    }
    lds[t] = s;
    __syncthreads();
    for (int off = 1; off < 256; off <<= 1) {
        int v = (t >= off) ? lds[t - off] : 0;
        __syncthreads();
        lds[t] += v;
        __syncthreads();
    }
    int run = lds[t] - s;  // exclusive prefix
    for (int j = 0; j < CHUNK; ++j) {
        int i = base + j;
        if (i < n) {
            offs[i] = run;
            cur[i] = run;
            run += counts[i];
        } else if (i == n) {
            offs[n] = run;
        }
    }
}

__global__ void __launch_bounds__(256) fill_k(const int* __restrict__ edges,
                                              int* __restrict__ cur_s, int* __restrict__ cur_o,
                                              int* __restrict__ perm_s, int* __restrict__ perm_o,
                                              int n) {
    int t = blockIdx.x * 256 + threadIdx.x;
    if (t >= n) return;
    int s = edges[2 * t];
    int o = edges[2 * t + 1];
    perm_s[atomicAdd(&cur_s[s], 1)] = t;
    perm_o[atomicAdd(&cur_o[o], 1)] = t;
}

// ---- streaming pool: one wave per object, contiguous CSR range, no atomics ----
// nst is in SORTED order (the SO-GEMM gathered A-rows through perm), so object
// `obj` owns the contiguous row range [offs[obj], offs[obj+1]).
// PASS 0: pooled[obj] = sum of nst rows (s endpoints), fp32
// PASS 1: pooled = (pooled + sum of o rows) / max(deg,1), fp32, in place.
template <int PASS>
__global__ void __launch_bounds__(256)
pool_k(const ushort_t* __restrict__ nst, const int* __restrict__ offs_s,
       const int* __restrict__ offs_o, float* __restrict__ pooled) {
    int wave = threadIdx.x >> 6;
    int lane = threadIdx.x & 63;
    int obj = blockIdx.x * 4 + wave;
    if (obj >= NOBJ) return;
    const int* offs = (PASS == 0) ? offs_s : offs_o;
    int s = offs[obj], e = offs[obj + 1];
    float acc[8];
#pragma unroll
    for (int j = 0; j < 8; ++j) acc[j] = 0.f;
    for (int i = s; i < e; ++i) {
        uint4 v = *(const uint4*)(nst + (size_t)i * 512 + lane * 8);  // 8 bf16 / lane
        acc[0] += __uint_as_float(v.x << 16);
        acc[1] += __uint_as_float(v.x & 0xffff0000u);
        acc[2] += __uint_as_float(v.y << 16);
        acc[3] += __uint_as_float(v.y & 0xffff0000u);
        acc[4] += __uint_as_float(v.z << 16);
        acc[5] += __uint_as_float(v.z & 0xffff0000u);
        acc[6] += __uint_as_float(v.w << 16);
        acc[7] += __uint_as_float(v.w & 0xffff0000u);
    }
    float* prow = pooled + (size_t)obj * 512 + lane * 8;
    if (PASS == 0) {
        *(float4*)(prow)     = make_float4(acc[0], acc[1], acc[2], acc[3]);
        *(float4*)(prow + 4) = make_float4(acc[4], acc[5], acc[6], acc[7]);
    } else {
        float4 a0 = *(const float4*)(prow);
        float4 a1 = *(const float4*)(prow + 4);
        int deg = (offs_s[obj + 1] - offs_s[obj]) + (offs_o[obj + 1] - offs_o[obj]);
        float inv = 1.f / (float)((deg > 1) ? deg : 1);
        *(float4*)(prow)     = make_float4((acc[0] + a0.x) * inv, (acc[1] + a0.y) * inv,
                                           (acc[2] + a0.z) * inv, (acc[3] + a0.w) * inv);
        *(float4*)(prow + 4) = make_float4((acc[4] + a1.x) * inv, (acc[5] + a1.y) * inv,
                                           (acc[6] + a1.z) * inv, (acc[7] + a1.w) * inv);
    }
}

// Generic 128x128 tile MFMA GEMM computing C[m][n] = sum_k A[m][k]*B[n][k]
// (A: M x K row-major bf16 with leading dim lda, B: N x K row-major bf16),
// mode-specialized A-source (fused gathers) and epilogue.
// MODE_OBJ is the 2-pass fused form: out = relu(A@Bw^T + bias) + A2@B2^T + bias2 (fp32).
template <int MODE>
__global__ void __launch_bounds__(256)
gtc_gemm(const ushort_t* __restrict__ A, const ushort_t* __restrict__ Bw,
         const float* __restrict__ bias,
         const ushort_t* __restrict__ A2, const ushort_t* __restrict__ B2,
         const float* __restrict__ bias2,
         const int* __restrict__ idx,   // edges (MODE_H) or row-permutation (MODE_SO)
         const ushort_t* __restrict__ objv, const ushort_t* __restrict__ predv,
         void* __restrict__ outv,
         int M, int K, int lda)
{
    // LDS granule layout [kg][row], 16B granules, kg-major: fragment
    // ds_read_b128 is conflict-free.
    __shared__ short8 sA[1024];   // 16 KB
    __shared__ short8 sB[1024];   // 16 KB
    __shared__ int sIdx[128];
    __shared__ int oIdx[128];

    const int tid  = threadIdx.x;
    const int lane = tid & 63;
    const int wave = tid >> 6;
    const int wm   = wave & 1;
    const int wn   = wave >> 1;
    const int quad = lane >> 4;
    const int lr   = lane & 15;

    // ---- bijective XCD swizzle (T1, m204 variant): round-robin lb%8 -> XCD;
    // give each XCD a contiguous work range so the nx n-blocks sharing one
    // A-tile land on the SAME XCD in adjacent slots (A-tile L2-hot).
    const int nx  = gridDim.x;
    const int nwg = nx * gridDim.y;
    {
    }
    const int lb   = blockIdx.y * nx + blockIdx.x;
    const int q    = nwg >> 3, r = nwg & 7;
    const int xcd  = lb & 7, slot = lb >> 3;
    const int w    = xcd * q + ((xcd < r) ? xcd : r) + slot;
    const int m0   = (w / nx) * 128;
    const int n0   = (w % nx) * 128;

    if (MODE == MODE_H) {
        if (tid < 128) {
            int t = m0 + tid;
            if (t >= M) t = M - 1;
            sIdx[tid] = idx[2 * t];
            oIdx[tid] = idx[2 * t + 1];
        }
        __syncthreads();
    } else if (MODE == MODE_SO) {
        if (tid < 128) {
            int t = m0 + tid;
            if (t >= M) t = M - 1;
            sIdx[tid] = idx[t];
        }
        __syncthreads();
    }

    // K-invariant staging geometry: granule g = i*256+tid -> kg = g>>7 (k-slice),
    // m = g&127 (row). Hoist all row-base pointers out of the K-loop.
    int mI[4], kgI[4];
#pragma unroll
    for (int i = 0; i < 4; ++i) {
        int g = i * 256 + tid;
        kgI[i] = g >> 7;
        mI[i]  = g & 127;
    }

    const ushort_t *bA0[4], *bA1[4], *bA2[4];
    if (MODE == MODE_H) {
#pragma unroll
        for (int i = 0; i < 4; ++i) {
            int m = mI[i];
            int t = m0 + m;
            if (t >= M) t = M - 1;
            bA0[i] = objv + (size_t)sIdx[m] * 512;           // + krow        (krow<512)
            bA1[i] = predv + (size_t)t * 512 - 512;          // + krow        (512..1023)
            bA2[i] = objv + (size_t)oIdx[m] * 512 - 1024;    // + krow        (1024..1535)
        }
    } else if (MODE == MODE_SO) {
#pragma unroll
        for (int i = 0; i < 4; ++i)
            bA0[i] = A + (size_t)sIdx[mI[i]] * (size_t)K;
    }

    float4v acc[4][4];
#pragma unroll
    for (int i = 0; i < 4; ++i)
#pragma unroll
        for (int j = 0; j < 4; ++j)
            acc[i][j] = (float4v){0.f, 0.f, 0.f, 0.f};

    const int npass = (MODE == MODE_OBJ) ? 2 : 1;
    for (int pass = 0; pass < npass; ++pass) {
        const ushort_t* Ap = (pass == 0) ? A : A2;
        const ushort_t* Bp = (pass == 0) ? Bw : B2;

        // per-pass row/col base pointers (K-invariant)
        const ushort_t *pA[4], *pB[4];
#pragma unroll
        for (int i = 0; i < 4; ++i) {
            if (MODE == MODE_SO) {
                pA[i] = bA0[i];
            } else if (MODE != MODE_H) {
                int rr = m0 + mI[i];
                if (rr >= M) rr = M - 1;
                pA[i] = Ap + (size_t)rr * (size_t)lda;
            }
            pB[i] = Bp + (size_t)(n0 + mI[i]) * (size_t)K;
        }

        for (int k0 = 0; k0 < K; k0 += 64) {
            __syncthreads();  // previous tile's compute done before restage
            // ---- stage A tile (128 rows x 64 k) ----
#pragma unroll
            for (int i = 0; i < 4; ++i) {
                int krow = k0 + kgI[i] * 8;
                const ushort_t* src;
                if (MODE == MODE_H)
                    src = (krow < 512)  ? bA0[i] + krow
                        : (krow < 1024) ? bA1[i] + krow
                        :                 bA2[i] + krow;
                else
                    src = pA[i] + krow;
                gload_lds16(src, &sA[i * 256 + tid]);
            }
            // ---- stage B tile (128 n x 64 k) ----
#pragma unroll
            for (int i = 0; i < 4; ++i)
                gload_lds16(pB[i] + k0 + kgI[i] * 8, &sB[i * 256 + tid]);
            __syncthreads();  // staging drained

#pragma unroll
            for (int kk = 0; kk < 2; ++kk) {
                short8 af[4], bfv[4];
#pragma unroll
                for (int t = 0; t < 4; ++t)
                    af[t] = sA[(kk * 4 + quad) * 128 + wm * 64 + t * 16 + lr];
#pragma unroll
                for (int t = 0; t < 4; ++t)
                    bfv[t] = sB[(kk * 4 + quad) * 128 + wn * 64 + t * 16 + lr];
#pragma unroll
                for (int ti = 0; ti < 4; ++ti)
#pragma unroll
                    for (int tj = 0; tj < 4; ++tj)
                        acc[ti][tj] = __builtin_amdgcn_mfma_f32_16x16x32_bf16(
                            af[ti], bfv[tj], acc[ti][tj], 0, 0, 0);
            }
        }

        if (MODE == MODE_OBJ && pass == 0) {
            // acc = relu(acc + bias[col]) between the two fused GEMMs
#pragma unroll
            for (int tj = 0; tj < 4; ++tj) {
                float b = bias[n0 + wn * 64 + tj * 16 + lr];
#pragma unroll
                for (int ti = 0; ti < 4; ++ti)
#pragma unroll
                    for (int r = 0; r < 4; ++r)
                        acc[ti][tj][r] = fmaxf(acc[ti][tj][r] + b, 0.f);
            }
        }
    }

    // ---- epilogue ----
    float bcol[4];
#pragma unroll
    for (int tj = 0; tj < 4; ++tj) {
        int col = n0 + wn * 64 + tj * 16 + lr;
        const float* bptr = (MODE == MODE_OBJ) ? bias2 : bias;
        bcol[tj] = bptr[col];
    }

#pragma unroll
    for (int ti = 0; ti < 4; ++ti) {
#pragma unroll
        for (int r = 0; r < 4; ++r) {
            int row = m0 + wm * 64 + ti * 16 + quad * 4 + r;
            if (row >= M) continue;
#pragma unroll
            for (int tj = 0; tj < 4; ++tj) {
                int col = n0 + wn * 64 + tj * 16 + lr;
                float v = acc[ti][tj][r];
                if (MODE == MODE_OBJ) {
                    ((float*)outv)[(size_t)row * 512 + col] = v + bcol[tj];
                } else {  // MODE_H / MODE_G / MODE_SO: relu + bf16
                    v = fmaxf(v + bcol[tj], 0.f);
                    ((ushort_t*)outv)[(size_t)row * 512 + col] = f2bf(v);
                }
            }
        }
    }
}

extern "C" void kernel_launch(void* const* d_in, const int* in_sizes, int n_in,
                              void* d_out, int out_size, void* d_ws, size_t ws_size,
                              hipStream_t stream) {
    const float* obj    = (const float*)d_in[0];
    const float* pred   = (const float*)d_in[1];
    const int*   edges  = (const int*)d_in[2];
    const float* W1     = (const float*)d_in[3];
    const float* b1     = (const float*)d_in[4];
    const float* W2     = (const float*)d_in[5];
    const float* b2     = (const float*)d_in[6];
    const float* V1     = (const float*)d_in[7];
    const float* c1     = (const float*)d_in[8];
    const float* V2     = (const float*)d_in[9];
    const float* c2     = (const float*)d_in[10];
    const float* Pobj   = (const float*)d_in[11];
    const float* pbobj  = (const float*)d_in[12];
    const float* Ppred  = (const float*)d_in[13];
    const float* pbpred = (const float*)d_in[14];

    // ---- workspace layout (total 230,522,880 B — within the known-good
    // 230.6 MB footprint) ----
    char* ws = (char*)d_ws;
    ushort_t* h       = (ushort_t*)(ws + 0);              // 102,400,000 B (dead after SO-o)
    ushort_t* bfPred  = (ushort_t*)(ws + 102400000);      // 102,400,000 B (dead after P-fused)
    ushort_t* nst     = bfPred;                           // new_s / new_o bf16, aliases bfPred
    ushort_t* bfObj   = (ushort_t*)(ws + 204800000);      //  20,480,000 B
    ushort_t* bfW1    = (ushort_t*)(ws + 225280000);      //   1,572,864 B (dead after GEMM1)
    // CSR structures alias the dead bfW1 region (built after GEMM1):
    char* csr = ws + 225280000;
    int* counts_s = (int*)(csr + 0);        //  80,000 B
    int* counts_o = (int*)(csr + 80000);    //  80,000 B
    int* offs_s   = (int*)(csr + 160000);   //  80,064 B (20001 ints)
    int* offs_o   = (int*)(csr + 240064);   //  80,064 B
    int* cur_s    = (int*)(csr + 320128);   //  80,000 B
    int* cur_o    = (int*)(csr + 400128);   //  80,000 B
    int* perm_s   = (int*)(csr + 480128);   // 400,000 B
    int* perm_o   = (int*)(csr + 880128);   // 400,000 B -> ends +1,280,128 < 1,572,864
    ushort_t* bfW2    = (ushort_t*)(ws + 226852864);      //   1,572,864 B
    ushort_t* bfV1    = (ushort_t*)(ws + 228425728);      //     524,288 B
    ushort_t* bfV2    = (ushort_t*)(ws + 228950016);      //     524,288 B
    ushort_t* bfPobj  = (ushort_t*)(ws + 229474304);      //     524,288 B
    ushort_t* bfPpred = (ushort_t*)(ws + 229998592);      //     524,288 B -> 230,522,880
    // aliases into the dead h region (only touched after SO-o retires h):
    ushort_t* pooledn = (ushort_t*)(ws + 0);              //  20,480,000 B
    ushort_t* gbuf    = (ushort_t*)(ws + 20480000);       //  20,480,000 B

    float* out_obj = (float*)d_out;
    float* out_p   = out_obj + (size_t)NOBJ * 512;
    // fp32 pooled accumulators live in the out_obj region of d_out (exactly
    // 40,960,000 B); dead after the cvt to pooledn; MODE_OBJ then overwrites.
    float* pooled = out_obj;

    // fp32 -> bf16 conversions
    cvt_k<<<dim3(10000), dim3(256), 0, stream>>>(obj,   bfObj,   10240000 / 4);
    cvt_k<<<dim3(50000), dim3(256), 0, stream>>>(pred,  bfPred,  51200000 / 4);
    cvt_k<<<dim3(768),   dim3(256), 0, stream>>>(W1,    bfW1,    786432 / 4);
    cvt_k<<<dim3(768),   dim3(256), 0, stream>>>(W2,    bfW2,    786432 / 4);
    cvt_k<<<dim3(256),   dim3(256), 0, stream>>>(V1,    bfV1,    262144 / 4);
    cvt_k<<<dim3(256),   dim3(256), 0, stream>>>(V2,    bfV2,    262144 / 4);
    cvt_k<<<dim3(256),   dim3(256), 0, stream>>>(Pobj,  bfPobj,  262144 / 4);
    cvt_k<<<dim3(256),   dim3(256), 0, stream>>>(Ppred, bfPpred, 262144 / 4);

    // GEMM1: h = relu(gather(cur_t) @ W1^T + b1)    (100000 x 512, K=1536)
    gtc_gemm<MODE_H><<<dim3(4, 782), dim3(256), 0, stream>>>(
        nullptr, bfW1, b1, nullptr, nullptr, nullptr,
        edges, bfObj, bfPred, h, NTRI, 1536, 1536);

    // ---- CSR build (bfW1 dead now) ----
    hipMemsetAsync(counts_s, 0, 160000, stream);  // counts_s + counts_o
    hist_k<<<dim3(782), dim3(256), 0, stream>>>(edges, counts_s, counts_o, 2 * NTRI);
    scan_k<<<dim3(1), dim3(256), 0, stream>>>(counts_s, offs_s, cur_s, NOBJ);
    scan_k<<<dim3(1), dim3(256), 0, stream>>>(counts_o, offs_o, cur_o, NOBJ);
    fill_k<<<dim3(391), dim3(256), 0, stream>>>(edges, cur_s, cur_o, perm_s, perm_o, NTRI);

    // P-fused (2-pass MODE_OBJ, M=NTRI):
    //   out_p = relu(h @ W2_p^T + b2_p) + pred @ Ppred^T + pbpred
    // Last use of bfPred (frees it for the nst alias).
    gtc_gemm<MODE_OBJ><<<dim3(4, 782), dim3(256), 0, stream>>>(
        h, bfW2 + 512 * 512, b2 + 512, bfPred, bfPpred, pbpred,
        nullptr, nullptr, nullptr, out_p, NTRI, 512, 512);

    // GEMM2-s: new_s rows (permuted so same-object rows are contiguous) -> nst
    gtc_gemm<MODE_SO><<<dim3(4, 782), dim3(256), 0, stream>>>(
        h, bfW2, b2, nullptr, nullptr, nullptr,
        perm_s, nullptr, nullptr, nst, NTRI, 512, 512);
    pool_k<0><<<dim3(5000), dim3(256), 0, stream>>>(nst, offs_s, offs_o, pooled);

    // GEMM2-o: new_o rows -> nst (reused).  Last use of h.
    gtc_gemm<MODE_SO><<<dim3(4, 782), dim3(256), 0, stream>>>(
        h, bfW2 + 1024 * 512, b2 + 1024, nullptr, nullptr, nullptr,
        perm_o, nullptr, nullptr, nst, NTRI, 512, 512);
    pool_k<1><<<dim3(5000), dim3(256), 0, stream>>>(nst, offs_s, offs_o, pooled);

    // pooled fp32 -> pooledn bf16 (contiguous 512-stride, in dead h region)
    cvt_k<<<dim3(10000), dim3(256), 0, stream>>>(pooled, pooledn, 10240000 / 4);

    // GEMM3: g = relu(pooledn @ V1^T + c1)   (20000 x 512, K=512)
    gtc_gemm<MODE_G><<<dim3(4, 157), dim3(256), 0, stream>>>(
        pooledn, bfV1, c1, nullptr, nullptr, nullptr,
        nullptr, nullptr, nullptr, gbuf, NOBJ, 512, 512);

    // GEMM4+5 fused: out_obj = relu(g @ V2^T + c2) + obj @ P_obj^T + pb_obj
    // (overwrites the pooled region — pooled is dead after the cvt)
    gtc_gemm<MODE_OBJ><<<dim3(4, 157), dim3(256), 0, stream>>>(
        gbuf, bfV2, c2, bfObj, bfPobj, pbobj,
        nullptr, nullptr, nullptr, out_obj, NOBJ, 512, 512);
}